// Round 15
// baseline (427.590 us; speedup 1.0000x reference)
//
#include <hip/hip_runtime.h>
#include <cstdint>
#include <cstddef>

typedef unsigned short u16;
typedef unsigned int u32;

using short8 = __attribute__((ext_vector_type(8))) short;
using f32x4  = __attribute__((ext_vector_type(4))) float;

__device__ __forceinline__ float b2f(u16 v) {
  union { u32 u; float f; } c; c.u = ((u32)v) << 16; return c.f;
}
__device__ __forceinline__ u16 f2b(float f) {
  union { float f; u32 u; } c; c.f = f;
  u32 u = c.u;
  u += 0x7fffu + ((u >> 16) & 1u);   // round-to-nearest-even
  return (u16)(u >> 16);
}

// ---------------- fp32 row-major -> bf16 tile-layout (128 cols) ----------------
__global__ __launch_bounds__(256)
void f2bf_kernel(const float* __restrict__ in, u16* __restrict__ outp) {
  int i = blockIdx.x * 256 + threadIdx.x;
  int el = i * 2;
  int m = ((el >> 11) << 4) | ((el >> 5) & 15);
  int n = (((el >> 9) & 3) << 5) | (el & 31);
  float2 v = *(const float2*)(in + (size_t)m * 128 + n);
  *(u32*)(outp + el) = (u32)f2b(v.x) | ((u32)f2b(v.y) << 16);
}

// ---------------- weight prep: W[K,N] fp32 -> Bt tile-layout bf16 ----------------
__global__ __launch_bounds__(256)
void prep_kernel(const float* __restrict__ Wl1, const float* __restrict__ Wl2,
                 const float* __restrict__ Wq,  const float* __restrict__ Wk,
                 const float* __restrict__ Wv,  const float* __restrict__ Wo,
                 const float* __restrict__ Wf1, const float* __restrict__ Wf2,
                 const float* __restrict__ bl1, const float* __restrict__ bl2,
                 const float* __restrict__ bq,  const float* __restrict__ bk,
                 const float* __restrict__ bv,  const float* __restrict__ bo,
                 const float* __restrict__ bf1, const float* __restrict__ bf2,
                 u16* __restrict__ Bt, float* __restrict__ biasAll) {
  int idx = blockIdx.x * 256 + threadIdx.x;
  if (idx < 196608) {
    const float* W; int local, K, N;
    if      (idx <  32768) { W = Wl1; local = idx;          K = 128; N = 256; }
    else if (idx <  65536) { W = Wl2; local = idx - 32768;  K = 256; N = 128; }
    else if (idx <  81920) { W = Wq;  local = idx - 65536;  K = 128; N = 128; }
    else if (idx <  98304) { W = Wk;  local = idx - 81920;  K = 128; N = 128; }
    else if (idx < 114688) { W = Wv;  local = idx - 98304;  K = 128; N = 128; }
    else if (idx < 131072) { W = Wo;  local = idx - 114688; K = 128; N = 128; }
    else if (idx < 163840) { W = Wf1; local = idx - 131072; K = 128; N = 256; }
    else                   { W = Wf2; local = idx - 163840; K = 256; N = 128; }
    int ks2 = (K == 256) ? 3 : 2;          // k-tiles per n-tile-row
    int tile = local >> 9, within = local & 511;
    int nr = within >> 5, kc = within & 31;
    int n = ((tile >> ks2) << 4) + nr;
    int k = ((tile & ((1 << ks2) - 1)) << 5) + kc;
    Bt[idx] = f2b(W[(size_t)k * N + n]);
  }
  int t = idx - 196608;
  if (t >= 0 && t < 1280) {
    float v;
    if      (t <  256) v = bl1[t];
    else if (t <  384) v = bl2[t - 256];
    else if (t <  512) v = bq[t - 384];
    else if (t <  640) v = bk[t - 512];
    else if (t <  768) v = bv[t - 640];
    else if (t <  896) v = bo[t - 768];
    else if (t < 1152) v = bf1[t - 896];
    else               v = bf2[t - 1152];
    biasAll[t] = v;
  }
}

// ---------------- CSR build ----------------
__global__ void hist_kernel(const int* __restrict__ dst, int* __restrict__ deg, int E) {
  int i = blockIdx.x * 256 + threadIdx.x;
  if (i < E) atomicAdd(&deg[dst[i]], 1);
}

__global__ __launch_bounds__(256)
void scan1_kernel(const int* __restrict__ deg, int* __restrict__ bsum) {
  int t = threadIdx.x, b = blockIdx.x;
  int v = deg[b * 256 + t];
#pragma unroll
  for (int off = 1; off < 64; off <<= 1) v += __shfl_xor(v, off);
  __shared__ int wsum[4];
  if ((t & 63) == 0) wsum[t >> 6] = v;
  __syncthreads();
  if (t == 0) bsum[b] = wsum[0] + wsum[1] + wsum[2] + wsum[3];
}

__global__ void scan2_kernel(const int* __restrict__ bsum, int* __restrict__ boff,
                             int* __restrict__ rowptrN) {
  __shared__ int sh[128];
  int t = threadIdx.x;
  int v = bsum[t];
  sh[t] = v;
  __syncthreads();
  for (int off = 1; off < 128; off <<= 1) {
    int u = (t >= off) ? sh[t - off] : 0;
    __syncthreads();
    sh[t] += u;
    __syncthreads();
  }
  boff[t] = sh[t] - v;
  if (t == 127) *rowptrN = sh[127];
}

__global__ __launch_bounds__(256)
void scan3_kernel(const int* __restrict__ deg, const int* __restrict__ boff,
                  int* __restrict__ rowptr, int* __restrict__ cursor) {
  __shared__ int sh[256];
  int t = threadIdx.x, b = blockIdx.x;
  int idx = b * 256 + t;
  int v = deg[idx];
  sh[t] = v;
  __syncthreads();
  for (int off = 1; off < 256; off <<= 1) {
    int u = (t >= off) ? sh[t - off] : 0;
    __syncthreads();
    sh[t] += u;
    __syncthreads();
  }
  int ex = sh[t] - v + boff[b];
  rowptr[idx] = ex;
  cursor[idx] = ex;
}

__global__ void scatter_kernel(const int* __restrict__ src, const int* __restrict__ dst,
                               int* __restrict__ cursor, int* __restrict__ csr, int E) {
  int i = blockIdx.x * 256 + threadIdx.x;
  if (i < E) {
    int d = dst[i];
    int pos = atomicAdd(&cursor[d], 1);
    csr[pos] = src[i];
  }
}

// -------- aggregate neighbours (bf16 tile-layout gather) + (1+eps)*x --------
__global__ __launch_bounds__(256)
void agg_kernel(const u16* __restrict__ xb, const float* __restrict__ x,
                const int* __restrict__ csr, const int* __restrict__ rowptr,
                const float* __restrict__ eps, u16* __restrict__ hin, int N) {
  int node = blockIdx.x * 4 + (threadIdx.x >> 6);
  if (node >= N) return;
  int lane = threadIdx.x & 63;
  int laneoff = (lane >> 4) * 512 + (lane & 15) * 2;   // tile-layout lane part
  float ep1 = 1.0f + eps[0];
  int s0 = rowptr[node], s1 = rowptr[node + 1];
  float a0 = 0.f, a1 = 0.f;
  int e = s0;
  for (; e + 4 <= s1; e += 4) {
    int i0 = csr[e], i1 = csr[e + 1], i2 = csr[e + 2], i3 = csr[e + 3];
    u32 w0 = *(const u32*)(xb + (size_t)(i0 >> 4) * 2048 + (i0 & 15) * 32 + laneoff);
    u32 w1 = *(const u32*)(xb + (size_t)(i1 >> 4) * 2048 + (i1 & 15) * 32 + laneoff);
    u32 w2 = *(const u32*)(xb + (size_t)(i2 >> 4) * 2048 + (i2 & 15) * 32 + laneoff);
    u32 w3 = *(const u32*)(xb + (size_t)(i3 >> 4) * 2048 + (i3 & 15) * 32 + laneoff);
    a0 += b2f((u16)w0) + b2f((u16)w1) + b2f((u16)w2) + b2f((u16)w3);
    a1 += b2f((u16)(w0 >> 16)) + b2f((u16)(w1 >> 16))
        + b2f((u16)(w2 >> 16)) + b2f((u16)(w3 >> 16));
  }
  for (; e < s1; e++) {
    int s = csr[e];
    u32 w = *(const u32*)(xb + (size_t)(s >> 4) * 2048 + (s & 15) * 32 + laneoff);
    a0 += b2f((u16)w);
    a1 += b2f((u16)(w >> 16));
  }
  float2 xw = *(const float2*)(x + (size_t)node * 128 + lane * 2);  // fp32 self-term
  a0 += ep1 * xw.x;
  a1 += ep1 * xw.y;
  *(u32*)(hin + (size_t)(node >> 4) * 2048 + (node & 15) * 32 + laneoff)
      = (u32)f2b(a0) | ((u32)f2b(a1) << 16);
}

// ---------------- tile-layout MFMA GEMM v3 (round-13, unchanged) ----------------
template<int K>
__global__ __launch_bounds__(256)
void gemm_fast(const u16* __restrict__ A, const u16* __restrict__ Bt,
               const float* __restrict__ bias, const u16* __restrict__ residb,
               u16* __restrict__ C0, u16* __restrict__ C1, u16* __restrict__ C2,
               float* __restrict__ ssum, float* __restrict__ ssq,
               int ntshift, int relu, float scale0, int headmajor) {
  const int tid = threadIdx.x, wave = tid >> 6, lane = tid & 63;
  const int quad = lane >> 4, c = lane & 15;
  const int y = blockIdx.y;
  const int ti = y >> ntshift, ntv = y & ((1 << ntshift) - 1);
  const int Nout = 32 << ntshift;
  const int nc32 = Nout >> 5;
  constexpr int KT = K >> 5;
  const u16* Btp = Bt + (size_t)ti * Nout * K;
  const float* bp = bias + ti * Nout;
  u16* C = (ti == 0) ? C0 : ((ti == 1) ? C1 : C2);
  const float scl = (ti == 0) ? scale0 : 1.0f;
  const int row0 = blockIdx.x * 128 + wave * 32;
  const int mt0 = row0 >> 4;
  const int col0 = ntv * 32;
  const int loff = c * 32 + quad * 8;

  const u16* Ap0 = A   + (size_t)(mt0)     * KT * 512 + loff;
  const u16* Ap1 = A   + (size_t)(mt0 + 1) * KT * 512 + loff;
  const u16* Bp0 = Btp + (size_t)(ntv * 2)     * KT * 512 + loff;
  const u16* Bp1 = Btp + (size_t)(ntv * 2 + 1) * KT * 512 + loff;

  f32x4 acc[2][2];
#pragma unroll
  for (int i = 0; i < 2; i++)
#pragma unroll
    for (int j = 0; j < 2; j++)
#pragma unroll
      for (int r = 0; r < 4; r++) acc[i][j][r] = 0.f;

#pragma unroll
  for (int i = 0; i < KT; i++) {
    short8 a0 = *(const short8*)(Ap0 + i * 512);
    short8 a1 = *(const short8*)(Ap1 + i * 512);
    short8 b0 = *(const short8*)(Bp0 + i * 512);
    short8 b1 = *(const short8*)(Bp1 + i * 512);
    acc[0][0] = __builtin_amdgcn_mfma_f32_16x16x32_bf16(a0, b0, acc[0][0], 0, 0, 0);
    acc[0][1] = __builtin_amdgcn_mfma_f32_16x16x32_bf16(a0, b1, acc[0][1], 0, 0, 0);
    acc[1][0] = __builtin_amdgcn_mfma_f32_16x16x32_bf16(a1, b0, acc[1][0], 0, 0, 0);
    acc[1][1] = __builtin_amdgcn_mfma_f32_16x16x32_bf16(a1, b1, acc[1][1], 0, 0, 0);
  }

#pragma unroll
  for (int ci = 0; ci < 2; ci++) {
    int col = col0 + ci * 16 + c;
    float bv = bp[col];
    float sp = 0.f, qp = 0.f;
#pragma unroll
    for (int mi = 0; mi < 2; mi++) {
#pragma unroll
      for (int r = 0; r < 4; r++) {
        int m = row0 + mi * 16 + quad * 4 + r;
        float v = acc[mi][ci][r] + bv;
        if (relu) v = fmaxf(v, 0.f);
        if (residb)
          v += b2f(residb[((size_t)(mt0 + mi) * 4 + (col >> 5)) * 512
                          + (quad * 4 + r) * 32 + (col & 31)]);
        v *= scl;
        size_t cidx;
        if (headmajor) {
          int bb = m >> 9, j = m & 511;
          cidx = (size_t)(bb * 8 + (col >> 4)) * 8192 + (size_t)j * 16 + (col & 15);
        } else {
          cidx = ((size_t)(mt0 + mi) * nc32 + ntv) * 512
               + (quad * 4 + r) * 32 + ci * 16 + c;
        }
        C[cidx] = f2b(v);
        sp += v; qp += v * v;
      }
    }
    if (ssum) {
      sp += __shfl_xor(sp, 16); sp += __shfl_xor(sp, 32);
      qp += __shfl_xor(qp, 16); qp += __shfl_xor(qp, 32);
      if (quad == 0) {
        atomicAdd(&ssum[col], sp);
        atomicAdd(&ssq[col], qp);
      }
    }
  }
}

// ---------------- MFMA attention v7 ----------------
// Round-14 counters: VALU 70%, conflicts 2.1M, FETCH 20.6MB (global-K OK in
// head-major). Remaining VALU/LDS mass = V staging (8192 scalar u16 scatter
// stores/block). v7: exploit that the j-interleave maps rows (j, j+16) to
// ADJACENT j' slots -> each thread owns a (row-pair, d-half) and emits 8
// packed u32 writes (4096 stores/block, all <=2-way bank aliasing = free).
// Also: Q frags for both qt hoisted; jp loop unroll 4 to pipeline K loads.
__global__ __launch_bounds__(512)
void attn_kernel(const u16* __restrict__ Q, const u16* __restrict__ Km,
                 const u16* __restrict__ Vm, u16* __restrict__ O) {
  __shared__ __align__(16) u16 Vt[16 * 520];    // V^T [d][j'], row stride 520
  __shared__ __align__(16) u16 Psh[8][16 * 40]; // per-wave P
  const int bh = blockIdx.x >> 1, qhalf = blockIdx.x & 1;
  const int b = bh >> 3, hh = bh & 7;
  const size_t qkvbase = (size_t)bh * 8192;               // [b][h][512][16]
  const int tid = threadIdx.x;

  {
    // thread -> (j-group g of 32, row i in [0,16), d-half dh)
    int g = tid >> 5, i = (tid >> 1) & 15, dh = tid & 1;
    int jA = g * 32 + i;                         // pairs with jA+16
    const u16* vp = Vm + qkvbase + (size_t)jA * 16 + dh * 8;
    short8 rowA = *(const short8*)(vp);          // 16B, coalesced across wave
    short8 rowB = *(const short8*)(vp + 256);    // row jA+16, same d-half
    int j2 = g * 32 + 2 * i;                     // interleaved: rowA->j2, rowB->j2+1
#pragma unroll
    for (int d = 0; d < 8; d++)
      *(u32*)&Vt[(dh * 8 + d) * 520 + j2] =
          (u32)(u16)rowA[d] | ((u32)(u16)rowB[d] << 16);
  }
  __syncthreads();

  const int wave = tid >> 6, lane = tid & 63;
  const int quad = lane >> 4, c = lane & 15;
  u16* Pw = &Psh[wave][0];
  u32* Pw32 = (u32*)Pw;

  short8 ones;
#pragma unroll
  for (int i = 0; i < 8; i++) ones[i] = (short)0x3F80;   // bf16 1.0
  const f32x4 zero = {0.f, 0.f, 0.f, 0.f};

  // hoist both qt-iterations' Q frags
  short8 qf[2] = {(short8)0, (short8)0};
#pragma unroll
  for (int t = 0; t < 2; t++) {
    int qt = qhalf * 16 + wave + t * 8;
    if (quad < 2)
      qf[t] = *(const short8*)(Q + qkvbase + (size_t)(qt * 16 + c) * 16 + quad * 8);
  }

#pragma unroll
  for (int t = 0; t < 2; t++) {
    const int qt = qhalf * 16 + wave + t * 8;
    f32x4 accO = zero, accL = zero;
#pragma unroll 4
    for (int jp = 0; jp < 16; jp++) {
      short8 kf0 = (short8)0, kf1 = (short8)0;
      if (quad < 2) {
        kf0 = *(const short8*)(Km + qkvbase + (size_t)(jp * 32 + c) * 16 + quad * 8);
        kf1 = *(const short8*)(Km + qkvbase + (size_t)(jp * 32 + 16 + c) * 16 + quad * 8);
      }
      f32x4 s0 = __builtin_amdgcn_mfma_f32_16x16x32_bf16(qf[t], kf0, zero, 0, 0, 0);
      f32x4 s1 = __builtin_amdgcn_mfma_f32_16x16x32_bf16(qf[t], kf1, zero, 0, 0, 0);
#pragma unroll
      for (int r = 0; r < 4; r++) {
        union { float f; u32 u; } u0, u1;
        u0.f = exp2f(s0[r]);
        u1.f = exp2f(s1[r]);
        Pw32[(quad * 4 + r) * 20 + c] = (u0.u >> 16) | (u1.u & 0xffff0000u);
      }
      short8 pf = *(const short8*)&Pw[c * 40 + quad * 8];
      short8 vf = *(const short8*)&Vt[c * 520 + jp * 32 + quad * 8];
      accO = __builtin_amdgcn_mfma_f32_16x16x32_bf16(pf, vf, accO, 0, 0, 0);
      accL = __builtin_amdgcn_mfma_f32_16x16x32_bf16(pf, ones, accL, 0, 0, 0);
    }
    // O element (m = b*512 + qt*16 + quad*4 + r, n = hh*16 + c) in tile layout
#pragma unroll
    for (int r = 0; r < 4; r++) {
      float o = accO[r] / accL[r];
      size_t oidx = ((size_t)(b * 32 + qt) * 4 + (hh >> 1)) * 512
                  + (quad * 4 + r) * 32 + (hh & 1) * 16 + c;
      O[oidx] = f2b(o);
    }
  }
}

// ---------------- fused BN elementwise (tile layout in/out) ----------------
__global__ __launch_bounds__(256)
void combine_kernel(const u16* __restrict__ y1, const u16* __restrict__ y2,
                    const float* __restrict__ stats,
                    const float* __restrict__ g1, const float* __restrict__ be1,
                    const float* __restrict__ g2, const float* __restrict__ be2,
                    u16* __restrict__ hout, float invM) {
  int i = blockIdx.x * 256 + threadIdx.x;
  int e0 = i * 2;
  int c = (((e0 >> 9) & 3) << 5) | (e0 & 31);   // column in [0,128)
  float sc1a, sh1a, sc1b, sh1b, sc2a, sh2a, sc2b, sh2b;
  {
    float m = stats[c] * invM, vv = stats[128 + c] * invM - m * m;
    sc1a = g1[c] * rsqrtf(vv + 1e-5f); sh1a = be1[c] - m * sc1a;
    m = stats[c + 1] * invM; vv = stats[129 + c] * invM - m * m;
    sc1b = g1[c + 1] * rsqrtf(vv + 1e-5f); sh1b = be1[c + 1] - m * sc1b;
    m = stats[256 + c] * invM; vv = stats[384 + c] * invM - m * m;
    sc2a = g2[c] * rsqrtf(vv + 1e-5f); sh2a = be2[c] - m * sc2a;
    m = stats[257 + c] * invM; vv = stats[385 + c] * invM - m * m;
    sc2b = g2[c + 1] * rsqrtf(vv + 1e-5f); sh2b = be2[c + 1] - m * sc2b;
  }
  u32 w1 = *(const u32*)(y1 + e0);
  u32 w2 = *(const u32*)(y2 + e0);
  float r0 = b2f((u16)w1) * sc1a + sh1a + b2f((u16)w2) * sc2a + sh2a;
  float r1 = b2f((u16)(w1 >> 16)) * sc1b + sh1b + b2f((u16)(w2 >> 16)) * sc2b + sh2b;
  *(u32*)(hout + e0) = (u32)f2b(r0) | ((u32)f2b(r1) << 16);
}

// out = bn3(y3): y3 tile layout, out row-major fp32
__global__ __launch_bounds__(256)
void norm_kernel(const u16* __restrict__ y3, const float* __restrict__ stats3,
                 const float* __restrict__ g3, const float* __restrict__ be3,
                 float* __restrict__ outp, float invM) {
  int i = blockIdx.x * 256 + threadIdx.x;
  int e0 = i * 2;
  int m = ((e0 >> 11) << 4) | ((e0 >> 5) & 15);
  int c = (((e0 >> 9) & 3) << 5) | (e0 & 31);
  float mm = stats3[c] * invM, vv = stats3[128 + c] * invM - mm * mm;
  float sca = g3[c] * rsqrtf(vv + 1e-5f), sha = be3[c] - mm * sca;
  mm = stats3[c + 1] * invM; vv = stats3[129 + c] * invM - mm * mm;
  float scb = g3[c + 1] * rsqrtf(vv + 1e-5f), shb = be3[c + 1] - mm * scb;
  u32 w = *(const u32*)(y3 + e0);
  float2 r;
  r.x = b2f((u16)w) * sca + sha;
  r.y = b2f((u16)(w >> 16)) * scb + shb;
  *(float2*)(outp + (size_t)m * 128 + c) = r;
}

// ---------------- launch ----------------
extern "C" void kernel_launch(void* const* d_in, const int* in_sizes, int n_in,
                              void* d_out, int out_size, void* d_ws, size_t ws_size,
                              hipStream_t stream) {
  const float* x   = (const float*)d_in[0];
  const int*   ei  = (const int*)d_in[1];
  const float* eps = (const float*)d_in[2];
  const float* Wl1 = (const float*)d_in[3];  const float* bl1 = (const float*)d_in[4];
  const float* Wl2 = (const float*)d_in[5];  const float* bl2 = (const float*)d_in[6];
  const float* g1  = (const float*)d_in[7];  const float* be1 = (const float*)d_in[8];
  const float* Wq  = (const float*)d_in[9];  const float* bq  = (const float*)d_in[10];
  const float* Wk  = (const float*)d_in[11]; const float* bk  = (const float*)d_in[12];
  const float* Wv  = (const float*)d_in[13]; const float* bv  = (const float*)d_in[14];
  const float* Wo  = (const float*)d_in[15]; const float* bo  = (const float*)d_in[16];
  const float* g2  = (const float*)d_in[17]; const float* be2 = (const float*)d_in[18];
  const float* Wf1 = (const float*)d_in[19]; const float* bf1 = (const float*)d_in[20];
  const float* Wf2 = (const float*)d_in[21]; const float* bf2 = (const float*)d_in[22];
  const float* g3  = (const float*)d_in[23]; const float* be3 = (const float*)d_in[24];
  float* out = (float*)d_out;

  const int N = in_sizes[0] / 128;   // 32768
  const int E = in_sizes[1] / 2;     // 524288
  const size_t MB = 1048576;
  const float invM = 1.0f / (float)N;

  char* ws = (char*)d_ws;
  u16* hin = (u16*)(ws + 0);          // [N,128] tile; agg out, later o_attn
  u16* t1  = (u16*)(ws + 8 * MB);     // [N,256] tile; later t2. CSR overlays pre-GEMM:
  int* deg    = (int*)(ws + 8 * MB);
  int* rowptr = (int*)(ws + 8 * MB + 256 * 1024);
  int* cursor = (int*)(ws + 8 * MB + 512 * 1024);
  int* csr    = (int*)(ws + 8 * MB + 768 * 1024);  // E ints = 2MB
  u16* qb  = (u16*)(ws + 24 * MB);    // q (head-major); later h_comb (tile)
  u16* kb  = (u16*)(ws + 32 * MB);    // k (head-major); later y3 (tile)
  u16* vb  = (u16*)(ws + 40 * MB);    // v (head-major)
  u16* xb  = (u16*)(ws + 48 * MB);    // bf16 x (tile); later y2 in-place
  u16* y2  = xb;
  float* stats = (float*)(ws + 56 * MB);         // s1,q1,s2,q2,s3,q3 (6*128)
  int* bsum = (int*)(ws + 56 * MB + 8192);
  int* boff = (int*)(ws + 56 * MB + 8192 + 512);
  u16* y1 = (u16*)d_out;              // d_out[0..8MB) as bf16 tile scratch
  u16*   BtAll   = (u16*)((char*)d_out + 8 * MB);                // 384 KB W^T tiles
  float* biasAll = (float*)((char*)d_out + 8 * MB + 400 * 1024); // 5 KB

  hipMemsetAsync(deg, 0, (size_t)N * sizeof(int), stream);
  hipMemsetAsync(stats, 0, 6 * 128 * sizeof(float), stream);

  const int* srcv = ei;
  const int* dstv = ei + E;
  const float QSCL = 0.25f * 1.44269504088896f;   // score scale * log2(e)

  prep_kernel<<<774, 256, 0, stream>>>(Wl1, Wl2, Wq, Wk, Wv, Wo, Wf1, Wf2,
                                       bl1, bl2, bq, bk, bv, bo, bf1, bf2,
                                       BtAll, biasAll);
  f2bf_kernel<<<(N * 128 / 2) / 256, 256, 0, stream>>>(x, xb);
  hist_kernel<<<(E + 255) / 256, 256, 0, stream>>>(dstv, deg, E);
  scan1_kernel<<<N / 256, 256, 0, stream>>>(deg, bsum);
  scan2_kernel<<<1, 128, 0, stream>>>(bsum, boff, rowptr + N);
  scan3_kernel<<<N / 256, 256, 0, stream>>>(deg, boff, rowptr, cursor);
  scatter_kernel<<<(E + 255) / 256, 256, 0, stream>>>(srcv, dstv, cursor, csr, E);
  agg_kernel<<<N / 4, 256, 0, stream>>>(xb, x, csr, rowptr, eps, hin, N);

  dim3 blk(256);
  // t1 = relu(hin @ Wl1 + bl1)          Nout=256 (ntshift=3)
  gemm_fast<128><<<dim3(N / 128, 8), blk, 0, stream>>>(hin, BtAll + 0, biasAll + 0,
      nullptr, t1, nullptr, nullptr, nullptr, nullptr, 3, 1, 1.0f, 0);
  // y1 = xb + t1 @ Wl2 + bl2  (+stats1)  Nout=128
  gemm_fast<256><<<dim3(N / 128, 4), blk, 0, stream>>>(t1, BtAll + 32768, biasAll + 256,
      xb, y1, nullptr, nullptr, stats + 0, stats + 128, 2, 0, 1.0f, 0);
  // q,k,v fused (3 tensors), HEAD-MAJOR outputs; q pre-scaled by QSCL
  gemm_fast<128><<<dim3(N / 128, 12), blk, 0, stream>>>(xb, BtAll + 65536, biasAll + 384,
      nullptr, qb, kb, vb, nullptr, nullptr, 2, 0, QSCL, 1);
  // attention -> o_attn (tile layout, reuse hin); grid = (b,h) x 2 q-halves
  attn_kernel<<<(N / 512) * 8 * 2, dim3(512), 0, stream>>>(qb, kb, vb, hin);
  // y2 = xb + o_attn @ Wo + bo  (+stats2)  (in-place over xb, same-thread RMW)
  gemm_fast<128><<<dim3(N / 128, 4), blk, 0, stream>>>(hin, BtAll + 114688, biasAll + 768,
      xb, y2, nullptr, nullptr, stats + 256, stats + 384, 2, 0, 1.0f, 0);
  // h = bn1(y1) + bn2(y2)  -> qb   (BN params inline)
  combine_kernel<<<(N * 128 / 2) / 256, blk, 0, stream>>>(y1, y2, stats,
      g1, be1, g2, be2, qb, invM);
  // t2 = relu(h @ Wf1 + bf1)            Nout=256
  gemm_fast<128><<<dim3(N / 128, 8), blk, 0, stream>>>(qb, BtAll + 131072, biasAll + 896,
      nullptr, t1, nullptr, nullptr, nullptr, nullptr, 3, 1, 1.0f, 0);
  // y3 = qb + t2 @ Wf2 + bf2  (+stats3)  -> kb
  gemm_fast<256><<<dim3(N / 128, 4), blk, 0, stream>>>(t1, BtAll + 163840, biasAll + 1152,
      qb, kb, nullptr, nullptr, stats + 512, stats + 640, 2, 0, 1.0f, 0);
  // out = bn3(y3)   (BN params inline)
  norm_kernel<<<(N * 128 / 2) / 256, blk, 0, stream>>>(kb, stats + 512, g3, be3, out, invM);
}

// Round 16
// 426.345 us; speedup vs baseline: 1.0029x; 1.0029x over previous
//
#include <hip/hip_runtime.h>
#include <cstdint>
#include <cstddef>

typedef unsigned short u16;
typedef unsigned int u32;

using short8 = __attribute__((ext_vector_type(8))) short;
using f32x4  = __attribute__((ext_vector_type(4))) float;

__device__ __forceinline__ float b2f(u16 v) {
  union { u32 u; float f; } c; c.u = ((u32)v) << 16; return c.f;
}
__device__ __forceinline__ u16 f2b(float f) {
  union { float f; u32 u; } c; c.f = f;
  u32 u = c.u;
  u += 0x7fffu + ((u >> 16) & 1u);   // round-to-nearest-even
  return (u16)(u >> 16);
}

// ---------------- fp32 row-major -> bf16 tile-layout (128 cols) ----------------
__global__ __launch_bounds__(256)
void f2bf_kernel(const float* __restrict__ in, u16* __restrict__ outp) {
  int i = blockIdx.x * 256 + threadIdx.x;
  int el = i * 2;
  int m = ((el >> 11) << 4) | ((el >> 5) & 15);
  int n = (((el >> 9) & 3) << 5) | (el & 31);
  float2 v = *(const float2*)(in + (size_t)m * 128 + n);
  *(u32*)(outp + el) = (u32)f2b(v.x) | ((u32)f2b(v.y) << 16);
}

// ---------------- weight prep: W[K,N] fp32 -> Bt tile-layout bf16 ----------------
__global__ __launch_bounds__(256)
void prep_kernel(const float* __restrict__ Wl1, const float* __restrict__ Wl2,
                 const float* __restrict__ Wq,  const float* __restrict__ Wk,
                 const float* __restrict__ Wv,  const float* __restrict__ Wo,
                 const float* __restrict__ Wf1, const float* __restrict__ Wf2,
                 const float* __restrict__ bl1, const float* __restrict__ bl2,
                 const float* __restrict__ bq,  const float* __restrict__ bk,
                 const float* __restrict__ bv,  const float* __restrict__ bo,
                 const float* __restrict__ bf1, const float* __restrict__ bf2,
                 u16* __restrict__ Bt, float* __restrict__ biasAll) {
  int idx = blockIdx.x * 256 + threadIdx.x;
  if (idx < 196608) {
    const float* W; int local, K, N;
    if      (idx <  32768) { W = Wl1; local = idx;          K = 128; N = 256; }
    else if (idx <  65536) { W = Wl2; local = idx - 32768;  K = 256; N = 128; }
    else if (idx <  81920) { W = Wq;  local = idx - 65536;  K = 128; N = 128; }
    else if (idx <  98304) { W = Wk;  local = idx - 81920;  K = 128; N = 128; }
    else if (idx < 114688) { W = Wv;  local = idx - 98304;  K = 128; N = 128; }
    else if (idx < 131072) { W = Wo;  local = idx - 114688; K = 128; N = 128; }
    else if (idx < 163840) { W = Wf1; local = idx - 131072; K = 128; N = 256; }
    else                   { W = Wf2; local = idx - 163840; K = 256; N = 128; }
    int ks2 = (K == 256) ? 3 : 2;          // k-tiles per n-tile-row
    int tile = local >> 9, within = local & 511;
    int nr = within >> 5, kc = within & 31;
    int n = ((tile >> ks2) << 4) + nr;
    int k = ((tile & ((1 << ks2) - 1)) << 5) + kc;
    Bt[idx] = f2b(W[(size_t)k * N + n]);
  }
  int t = idx - 196608;
  if (t >= 0 && t < 1280) {
    float v;
    if      (t <  256) v = bl1[t];
    else if (t <  384) v = bl2[t - 256];
    else if (t <  512) v = bq[t - 384];
    else if (t <  640) v = bk[t - 512];
    else if (t <  768) v = bv[t - 640];
    else if (t <  896) v = bo[t - 768];
    else if (t < 1152) v = bf1[t - 896];
    else               v = bf2[t - 1152];
    biasAll[t] = v;
  }
}

// ---------------- CSR build ----------------
__global__ void hist_kernel(const int* __restrict__ dst, int* __restrict__ deg, int E) {
  int i = blockIdx.x * 256 + threadIdx.x;
  if (i < E) atomicAdd(&deg[dst[i]], 1);
}

__global__ __launch_bounds__(256)
void scan1_kernel(const int* __restrict__ deg, int* __restrict__ bsum) {
  int t = threadIdx.x, b = blockIdx.x;
  int v = deg[b * 256 + t];
#pragma unroll
  for (int off = 1; off < 64; off <<= 1) v += __shfl_xor(v, off);
  __shared__ int wsum[4];
  if ((t & 63) == 0) wsum[t >> 6] = v;
  __syncthreads();
  if (t == 0) bsum[b] = wsum[0] + wsum[1] + wsum[2] + wsum[3];
}

__global__ void scan2_kernel(const int* __restrict__ bsum, int* __restrict__ boff,
                             int* __restrict__ rowptrN) {
  __shared__ int sh[128];
  int t = threadIdx.x;
  int v = bsum[t];
  sh[t] = v;
  __syncthreads();
  for (int off = 1; off < 128; off <<= 1) {
    int u = (t >= off) ? sh[t - off] : 0;
    __syncthreads();
    sh[t] += u;
    __syncthreads();
  }
  boff[t] = sh[t] - v;
  if (t == 127) *rowptrN = sh[127];
}

__global__ __launch_bounds__(256)
void scan3_kernel(const int* __restrict__ deg, const int* __restrict__ boff,
                  int* __restrict__ rowptr, int* __restrict__ cursor) {
  __shared__ int sh[256];
  int t = threadIdx.x, b = blockIdx.x;
  int idx = b * 256 + t;
  int v = deg[idx];
  sh[t] = v;
  __syncthreads();
  for (int off = 1; off < 256; off <<= 1) {
    int u = (t >= off) ? sh[t - off] : 0;
    __syncthreads();
    sh[t] += u;
    __syncthreads();
  }
  int ex = sh[t] - v + boff[b];
  rowptr[idx] = ex;
  cursor[idx] = ex;
}

__global__ void scatter_kernel(const int* __restrict__ src, const int* __restrict__ dst,
                               int* __restrict__ cursor, int* __restrict__ csr, int E) {
  int i = blockIdx.x * 256 + threadIdx.x;
  if (i < E) {
    int d = dst[i];
    int pos = atomicAdd(&cursor[d], 1);
    csr[pos] = src[i];
  }
}

// -------- aggregate neighbours (bf16 tile-layout gather) + (1+eps)*x --------
__global__ __launch_bounds__(256)
void agg_kernel(const u16* __restrict__ xb, const float* __restrict__ x,
                const int* __restrict__ csr, const int* __restrict__ rowptr,
                const float* __restrict__ eps, u16* __restrict__ hin, int N) {
  int node = blockIdx.x * 4 + (threadIdx.x >> 6);
  if (node >= N) return;
  int lane = threadIdx.x & 63;
  int laneoff = (lane >> 4) * 512 + (lane & 15) * 2;   // tile-layout lane part
  float ep1 = 1.0f + eps[0];
  int s0 = rowptr[node], s1 = rowptr[node + 1];
  float a0 = 0.f, a1 = 0.f;
  int e = s0;
  for (; e + 4 <= s1; e += 4) {
    int i0 = csr[e], i1 = csr[e + 1], i2 = csr[e + 2], i3 = csr[e + 3];
    u32 w0 = *(const u32*)(xb + (size_t)(i0 >> 4) * 2048 + (i0 & 15) * 32 + laneoff);
    u32 w1 = *(const u32*)(xb + (size_t)(i1 >> 4) * 2048 + (i1 & 15) * 32 + laneoff);
    u32 w2 = *(const u32*)(xb + (size_t)(i2 >> 4) * 2048 + (i2 & 15) * 32 + laneoff);
    u32 w3 = *(const u32*)(xb + (size_t)(i3 >> 4) * 2048 + (i3 & 15) * 32 + laneoff);
    a0 += b2f((u16)w0) + b2f((u16)w1) + b2f((u16)w2) + b2f((u16)w3);
    a1 += b2f((u16)(w0 >> 16)) + b2f((u16)(w1 >> 16))
        + b2f((u16)(w2 >> 16)) + b2f((u16)(w3 >> 16));
  }
  for (; e < s1; e++) {
    int s = csr[e];
    u32 w = *(const u32*)(xb + (size_t)(s >> 4) * 2048 + (s & 15) * 32 + laneoff);
    a0 += b2f((u16)w);
    a1 += b2f((u16)(w >> 16));
  }
  float2 xw = *(const float2*)(x + (size_t)node * 128 + lane * 2);  // fp32 self-term
  a0 += ep1 * xw.x;
  a1 += ep1 * xw.y;
  *(u32*)(hin + (size_t)(node >> 4) * 2048 + (node & 15) * 32 + laneoff)
      = (u32)f2b(a0) | ((u32)f2b(a1) << 16);
}

// ---------------- tile-layout MFMA GEMM v3 (round-13, unchanged) ----------------
template<int K>
__global__ __launch_bounds__(256)
void gemm_fast(const u16* __restrict__ A, const u16* __restrict__ Bt,
               const float* __restrict__ bias, const u16* __restrict__ residb,
               u16* __restrict__ C0, u16* __restrict__ C1, u16* __restrict__ C2,
               float* __restrict__ ssum, float* __restrict__ ssq,
               int ntshift, int relu, float scale0, int headmajor) {
  const int tid = threadIdx.x, wave = tid >> 6, lane = tid & 63;
  const int quad = lane >> 4, c = lane & 15;
  const int y = blockIdx.y;
  const int ti = y >> ntshift, ntv = y & ((1 << ntshift) - 1);
  const int Nout = 32 << ntshift;
  const int nc32 = Nout >> 5;
  constexpr int KT = K >> 5;
  const u16* Btp = Bt + (size_t)ti * Nout * K;
  const float* bp = bias + ti * Nout;
  u16* C = (ti == 0) ? C0 : ((ti == 1) ? C1 : C2);
  const float scl = (ti == 0) ? scale0 : 1.0f;
  const int row0 = blockIdx.x * 128 + wave * 32;
  const int mt0 = row0 >> 4;
  const int col0 = ntv * 32;
  const int loff = c * 32 + quad * 8;

  const u16* Ap0 = A   + (size_t)(mt0)     * KT * 512 + loff;
  const u16* Ap1 = A   + (size_t)(mt0 + 1) * KT * 512 + loff;
  const u16* Bp0 = Btp + (size_t)(ntv * 2)     * KT * 512 + loff;
  const u16* Bp1 = Btp + (size_t)(ntv * 2 + 1) * KT * 512 + loff;

  f32x4 acc[2][2];
#pragma unroll
  for (int i = 0; i < 2; i++)
#pragma unroll
    for (int j = 0; j < 2; j++)
#pragma unroll
      for (int r = 0; r < 4; r++) acc[i][j][r] = 0.f;

#pragma unroll
  for (int i = 0; i < KT; i++) {
    short8 a0 = *(const short8*)(Ap0 + i * 512);
    short8 a1 = *(const short8*)(Ap1 + i * 512);
    short8 b0 = *(const short8*)(Bp0 + i * 512);
    short8 b1 = *(const short8*)(Bp1 + i * 512);
    acc[0][0] = __builtin_amdgcn_mfma_f32_16x16x32_bf16(a0, b0, acc[0][0], 0, 0, 0);
    acc[0][1] = __builtin_amdgcn_mfma_f32_16x16x32_bf16(a0, b1, acc[0][1], 0, 0, 0);
    acc[1][0] = __builtin_amdgcn_mfma_f32_16x16x32_bf16(a1, b0, acc[1][0], 0, 0, 0);
    acc[1][1] = __builtin_amdgcn_mfma_f32_16x16x32_bf16(a1, b1, acc[1][1], 0, 0, 0);
  }

#pragma unroll
  for (int ci = 0; ci < 2; ci++) {
    int col = col0 + ci * 16 + c;
    float bv = bp[col];
    float sp = 0.f, qp = 0.f;
#pragma unroll
    for (int mi = 0; mi < 2; mi++) {
#pragma unroll
      for (int r = 0; r < 4; r++) {
        int m = row0 + mi * 16 + quad * 4 + r;
        float v = acc[mi][ci][r] + bv;
        if (relu) v = fmaxf(v, 0.f);
        if (residb)
          v += b2f(residb[((size_t)(mt0 + mi) * 4 + (col >> 5)) * 512
                          + (quad * 4 + r) * 32 + (col & 31)]);
        v *= scl;
        size_t cidx;
        if (headmajor) {
          int bb = m >> 9, j = m & 511;
          cidx = (size_t)(bb * 8 + (col >> 4)) * 8192 + (size_t)j * 16 + (col & 15);
        } else {
          cidx = ((size_t)(mt0 + mi) * nc32 + ntv) * 512
               + (quad * 4 + r) * 32 + ci * 16 + c;
        }
        C[cidx] = f2b(v);
        sp += v; qp += v * v;
      }
    }
    if (ssum) {
      sp += __shfl_xor(sp, 16); sp += __shfl_xor(sp, 32);
      qp += __shfl_xor(qp, 16); qp += __shfl_xor(qp, 32);
      if (quad == 0) {
        atomicAdd(&ssum[col], sp);
        atomicAdd(&ssq[col], qp);
      }
    }
  }
}

// ---------------- MFMA attention v8 ----------------
// Round-15 lesson: staging is cold; the hot mass is the per-(qt,jp) loop.
// v8 merges the two qt passes into ONE jp sweep: kf0/kf1 loaded once and fed
// to both Q frags (K loads + addr VALU halved), vf loaded once for both PV
// MFMAs (Vt reads halved). P packing is one v_perm_b32 instead of shift/and/or.
__global__ __launch_bounds__(512)
void attn_kernel(const u16* __restrict__ Q, const u16* __restrict__ Km,
                 const u16* __restrict__ Vm, u16* __restrict__ O) {
  __shared__ __align__(16) u16 Vt[16 * 520];    // V^T [d][j'], row stride 520
  __shared__ __align__(16) u16 Psh[8][16 * 40]; // per-wave P
  const int bh = blockIdx.x >> 1, qhalf = blockIdx.x & 1;
  const int b = bh >> 3, hh = bh & 7;
  const size_t qkvbase = (size_t)bh * 8192;               // [b][h][512][16]
  const int tid = threadIdx.x;

  {
    int g = tid >> 5, i = (tid >> 1) & 15, dh = tid & 1;
    int jA = g * 32 + i;                         // pairs with jA+16
    const u16* vp = Vm + qkvbase + (size_t)jA * 16 + dh * 8;
    short8 rowA = *(const short8*)(vp);
    short8 rowB = *(const short8*)(vp + 256);
    int j2 = g * 32 + 2 * i;
#pragma unroll
    for (int d = 0; d < 8; d++)
      *(u32*)&Vt[(dh * 8 + d) * 520 + j2] =
          (u32)(u16)rowA[d] | ((u32)(u16)rowB[d] << 16);
  }
  __syncthreads();

  const int wave = tid >> 6, lane = tid & 63;
  const int quad = lane >> 4, c = lane & 15;
  u16* Pw = &Psh[wave][0];
  u32* Pw32 = (u32*)Pw;

  short8 ones;
#pragma unroll
  for (int i = 0; i < 8; i++) ones[i] = (short)0x3F80;   // bf16 1.0
  const f32x4 zero = {0.f, 0.f, 0.f, 0.f};

  // both qt-iterations' Q frags
  short8 qf0 = (short8)0, qf1 = (short8)0;
  const int qtA = qhalf * 16 + wave, qtB = qtA + 8;
  if (quad < 2) {
    qf0 = *(const short8*)(Q + qkvbase + (size_t)(qtA * 16 + c) * 16 + quad * 8);
    qf1 = *(const short8*)(Q + qkvbase + (size_t)(qtB * 16 + c) * 16 + quad * 8);
  }

  f32x4 accO0 = zero, accL0 = zero, accO1 = zero, accL1 = zero;
#pragma unroll 2
  for (int jp = 0; jp < 16; jp++) {
    short8 kf0 = (short8)0, kf1 = (short8)0;
    if (quad < 2) {
      kf0 = *(const short8*)(Km + qkvbase + (size_t)(jp * 32 + c) * 16 + quad * 8);
      kf1 = *(const short8*)(Km + qkvbase + (size_t)(jp * 32 + 16 + c) * 16 + quad * 8);
    }
    short8 vf = *(const short8*)&Vt[c * 520 + jp * 32 + quad * 8];
    // ---- qt A ----
    {
      f32x4 s0 = __builtin_amdgcn_mfma_f32_16x16x32_bf16(qf0, kf0, zero, 0, 0, 0);
      f32x4 s1 = __builtin_amdgcn_mfma_f32_16x16x32_bf16(qf0, kf1, zero, 0, 0, 0);
#pragma unroll
      for (int r = 0; r < 4; r++) {
        union { float f; u32 u; } u0, u1;
        u0.f = exp2f(s0[r]);
        u1.f = exp2f(s1[r]);
        Pw32[(quad * 4 + r) * 20 + c] = __builtin_amdgcn_perm(u1.u, u0.u, 0x07060302u);
      }
      short8 pf = *(const short8*)&Pw[c * 40 + quad * 8];
      accO0 = __builtin_amdgcn_mfma_f32_16x16x32_bf16(pf, vf, accO0, 0, 0, 0);
      accL0 = __builtin_amdgcn_mfma_f32_16x16x32_bf16(pf, ones, accL0, 0, 0, 0);
    }
    // ---- qt B (reuses kf0/kf1/vf) ----
    {
      f32x4 s0 = __builtin_amdgcn_mfma_f32_16x16x32_bf16(qf1, kf0, zero, 0, 0, 0);
      f32x4 s1 = __builtin_amdgcn_mfma_f32_16x16x32_bf16(qf1, kf1, zero, 0, 0, 0);
#pragma unroll
      for (int r = 0; r < 4; r++) {
        union { float f; u32 u; } u0, u1;
        u0.f = exp2f(s0[r]);
        u1.f = exp2f(s1[r]);
        Pw32[(quad * 4 + r) * 20 + c] = __builtin_amdgcn_perm(u1.u, u0.u, 0x07060302u);
      }
      short8 pf = *(const short8*)&Pw[c * 40 + quad * 8];
      accO1 = __builtin_amdgcn_mfma_f32_16x16x32_bf16(pf, vf, accO1, 0, 0, 0);
      accL1 = __builtin_amdgcn_mfma_f32_16x16x32_bf16(pf, ones, accL1, 0, 0, 0);
    }
  }
  // O (m = b*512 + qt*16 + quad*4 + r, n = hh*16 + c) in tile layout
#pragma unroll
  for (int r = 0; r < 4; r++) {
    float o0 = accO0[r] / accL0[r];
    size_t oidx0 = ((size_t)(b * 32 + qtA) * 4 + (hh >> 1)) * 512
                 + (quad * 4 + r) * 32 + (hh & 1) * 16 + c;
    O[oidx0] = f2b(o0);
    float o1 = accO1[r] / accL1[r];
    size_t oidx1 = ((size_t)(b * 32 + qtB) * 4 + (hh >> 1)) * 512
                 + (quad * 4 + r) * 32 + (hh & 1) * 16 + c;
    O[oidx1] = f2b(o1);
  }
}

// ---------------- fused BN elementwise (tile layout in/out) ----------------
__global__ __launch_bounds__(256)
void combine_kernel(const u16* __restrict__ y1, const u16* __restrict__ y2,
                    const float* __restrict__ stats,
                    const float* __restrict__ g1, const float* __restrict__ be1,
                    const float* __restrict__ g2, const float* __restrict__ be2,
                    u16* __restrict__ hout, float invM) {
  int i = blockIdx.x * 256 + threadIdx.x;
  int e0 = i * 2;
  int c = (((e0 >> 9) & 3) << 5) | (e0 & 31);   // column in [0,128)
  float sc1a, sh1a, sc1b, sh1b, sc2a, sh2a, sc2b, sh2b;
  {
    float m = stats[c] * invM, vv = stats[128 + c] * invM - m * m;
    sc1a = g1[c] * rsqrtf(vv + 1e-5f); sh1a = be1[c] - m * sc1a;
    m = stats[c + 1] * invM; vv = stats[129 + c] * invM - m * m;
    sc1b = g1[c + 1] * rsqrtf(vv + 1e-5f); sh1b = be1[c + 1] - m * sc1b;
    m = stats[256 + c] * invM; vv = stats[384 + c] * invM - m * m;
    sc2a = g2[c] * rsqrtf(vv + 1e-5f); sh2a = be2[c] - m * sc2a;
    m = stats[257 + c] * invM; vv = stats[385 + c] * invM - m * m;
    sc2b = g2[c + 1] * rsqrtf(vv + 1e-5f); sh2b = be2[c + 1] - m * sc2b;
  }
  u32 w1 = *(const u32*)(y1 + e0);
  u32 w2 = *(const u32*)(y2 + e0);
  float r0 = b2f((u16)w1) * sc1a + sh1a + b2f((u16)w2) * sc2a + sh2a;
  float r1 = b2f((u16)(w1 >> 16)) * sc1b + sh1b + b2f((u16)(w2 >> 16)) * sc2b + sh2b;
  *(u32*)(hout + e0) = (u32)f2b(r0) | ((u32)f2b(r1) << 16);
}

// out = bn3(y3): y3 tile layout, out row-major fp32
__global__ __launch_bounds__(256)
void norm_kernel(const u16* __restrict__ y3, const float* __restrict__ stats3,
                 const float* __restrict__ g3, const float* __restrict__ be3,
                 float* __restrict__ outp, float invM) {
  int i = blockIdx.x * 256 + threadIdx.x;
  int e0 = i * 2;
  int m = ((e0 >> 11) << 4) | ((e0 >> 5) & 15);
  int c = (((e0 >> 9) & 3) << 5) | (e0 & 31);
  float mm = stats3[c] * invM, vv = stats3[128 + c] * invM - mm * mm;
  float sca = g3[c] * rsqrtf(vv + 1e-5f), sha = be3[c] - mm * sca;
  mm = stats3[c + 1] * invM; vv = stats3[129 + c] * invM - mm * mm;
  float scb = g3[c + 1] * rsqrtf(vv + 1e-5f), shb = be3[c + 1] - mm * scb;
  u32 w = *(const u32*)(y3 + e0);
  float2 r;
  r.x = b2f((u16)w) * sca + sha;
  r.y = b2f((u16)(w >> 16)) * scb + shb;
  *(float2*)(outp + (size_t)m * 128 + c) = r;
}

// ---------------- launch ----------------
extern "C" void kernel_launch(void* const* d_in, const int* in_sizes, int n_in,
                              void* d_out, int out_size, void* d_ws, size_t ws_size,
                              hipStream_t stream) {
  const float* x   = (const float*)d_in[0];
  const int*   ei  = (const int*)d_in[1];
  const float* eps = (const float*)d_in[2];
  const float* Wl1 = (const float*)d_in[3];  const float* bl1 = (const float*)d_in[4];
  const float* Wl2 = (const float*)d_in[5];  const float* bl2 = (const float*)d_in[6];
  const float* g1  = (const float*)d_in[7];  const float* be1 = (const float*)d_in[8];
  const float* Wq  = (const float*)d_in[9];  const float* bq  = (const float*)d_in[10];
  const float* Wk  = (const float*)d_in[11]; const float* bk  = (const float*)d_in[12];
  const float* Wv  = (const float*)d_in[13]; const float* bv  = (const float*)d_in[14];
  const float* Wo  = (const float*)d_in[15]; const float* bo  = (const float*)d_in[16];
  const float* g2  = (const float*)d_in[17]; const float* be2 = (const float*)d_in[18];
  const float* Wf1 = (const float*)d_in[19]; const float* bf1 = (const float*)d_in[20];
  const float* Wf2 = (const float*)d_in[21]; const float* bf2 = (const float*)d_in[22];
  const float* g3  = (const float*)d_in[23]; const float* be3 = (const float*)d_in[24];
  float* out = (float*)d_out;

  const int N = in_sizes[0] / 128;   // 32768
  const int E = in_sizes[1] / 2;     // 524288
  const size_t MB = 1048576;
  const float invM = 1.0f / (float)N;

  char* ws = (char*)d_ws;
  u16* hin = (u16*)(ws + 0);          // [N,128] tile; agg out, later o_attn
  u16* t1  = (u16*)(ws + 8 * MB);     // [N,256] tile; later t2. CSR overlays pre-GEMM:
  int* deg    = (int*)(ws + 8 * MB);
  int* rowptr = (int*)(ws + 8 * MB + 256 * 1024);
  int* cursor = (int*)(ws + 8 * MB + 512 * 1024);
  int* csr    = (int*)(ws + 8 * MB + 768 * 1024);  // E ints = 2MB
  u16* qb  = (u16*)(ws + 24 * MB);    // q (head-major); later h_comb (tile)
  u16* kb  = (u16*)(ws + 32 * MB);    // k (head-major); later y3 (tile)
  u16* vb  = (u16*)(ws + 40 * MB);    // v (head-major)
  u16* xb  = (u16*)(ws + 48 * MB);    // bf16 x (tile); later y2 in-place
  u16* y2  = xb;
  float* stats = (float*)(ws + 56 * MB);         // s1,q1,s2,q2,s3,q3 (6*128)
  int* bsum = (int*)(ws + 56 * MB + 8192);
  int* boff = (int*)(ws + 56 * MB + 8192 + 512);
  u16* y1 = (u16*)d_out;              // d_out[0..8MB) as bf16 tile scratch
  u16*   BtAll   = (u16*)((char*)d_out + 8 * MB);                // 384 KB W^T tiles
  float* biasAll = (float*)((char*)d_out + 8 * MB + 400 * 1024); // 5 KB

  hipMemsetAsync(deg, 0, (size_t)N * sizeof(int), stream);
  hipMemsetAsync(stats, 0, 6 * 128 * sizeof(float), stream);

  const int* srcv = ei;
  const int* dstv = ei + E;
  const float QSCL = 0.25f * 1.44269504088896f;   // score scale * log2(e)

  prep_kernel<<<774, 256, 0, stream>>>(Wl1, Wl2, Wq, Wk, Wv, Wo, Wf1, Wf2,
                                       bl1, bl2, bq, bk, bv, bo, bf1, bf2,
                                       BtAll, biasAll);
  f2bf_kernel<<<(N * 128 / 2) / 256, 256, 0, stream>>>(x, xb);
  hist_kernel<<<(E + 255) / 256, 256, 0, stream>>>(dstv, deg, E);
  scan1_kernel<<<N / 256, 256, 0, stream>>>(deg, bsum);
  scan2_kernel<<<1, 128, 0, stream>>>(bsum, boff, rowptr + N);
  scan3_kernel<<<N / 256, 256, 0, stream>>>(deg, boff, rowptr, cursor);
  scatter_kernel<<<(E + 255) / 256, 256, 0, stream>>>(srcv, dstv, cursor, csr, E);
  agg_kernel<<<N / 4, 256, 0, stream>>>(xb, x, csr, rowptr, eps, hin, N);

  dim3 blk(256);
  // t1 = relu(hin @ Wl1 + bl1)          Nout=256 (ntshift=3)
  gemm_fast<128><<<dim3(N / 128, 8), blk, 0, stream>>>(hin, BtAll + 0, biasAll + 0,
      nullptr, t1, nullptr, nullptr, nullptr, nullptr, 3, 1, 1.0f, 0);
  // y1 = xb + t1 @ Wl2 + bl2  (+stats1)  Nout=128
  gemm_fast<256><<<dim3(N / 128, 4), blk, 0, stream>>>(t1, BtAll + 32768, biasAll + 256,
      xb, y1, nullptr, nullptr, stats + 0, stats + 128, 2, 0, 1.0f, 0);
  // q,k,v fused (3 tensors), HEAD-MAJOR outputs; q pre-scaled by QSCL
  gemm_fast<128><<<dim3(N / 128, 12), blk, 0, stream>>>(xb, BtAll + 65536, biasAll + 384,
      nullptr, qb, kb, vb, nullptr, nullptr, 2, 0, QSCL, 1);
  // attention -> o_attn (tile layout, reuse hin); grid = (b,h) x 2 q-halves
  attn_kernel<<<(N / 512) * 8 * 2, dim3(512), 0, stream>>>(qb, kb, vb, hin);
  // y2 = xb + o_attn @ Wo + bo  (+stats2)  (in-place over xb, same-thread RMW)
  gemm_fast<128><<<dim3(N / 128, 4), blk, 0, stream>>>(hin, BtAll + 114688, biasAll + 768,
      xb, y2, nullptr, nullptr, stats + 256, stats + 384, 2, 0, 1.0f, 0);
  // h = bn1(y1) + bn2(y2)  -> qb   (BN params inline)
  combine_kernel<<<(N * 128 / 2) / 256, blk, 0, stream>>>(y1, y2, stats,
      g1, be1, g2, be2, qb, invM);
  // t2 = relu(h @ Wf1 + bf1)            Nout=256
  gemm_fast<128><<<dim3(N / 128, 8), blk, 0, stream>>>(qb, BtAll + 131072, biasAll + 896,
      nullptr, t1, nullptr, nullptr, nullptr, nullptr, 3, 1, 1.0f, 0);
  // y3 = qb + t2 @ Wf2 + bf2  (+stats3)  -> kb
  gemm_fast<256><<<dim3(N / 128, 4), blk, 0, stream>>>(t1, BtAll + 163840, biasAll + 1152,
      qb, kb, nullptr, nullptr, stats + 512, stats + 640, 2, 0, 1.0f, 0);
  // out = bn3(y3)   (BN params inline)
  norm_kernel<<<(N * 128 / 2) / 256, blk, 0, stream>>>(kb, stats + 512, g3, be3, out, invM);
}

// Round 17
// 413.231 us; speedup vs baseline: 1.0347x; 1.0317x over previous
//
#include <hip/hip_runtime.h>
#include <cstdint>
#include <cstddef>

typedef unsigned short u16;
typedef unsigned int u32;

using short8 = __attribute__((ext_vector_type(8))) short;
using f32x4  = __attribute__((ext_vector_type(4))) float;

__device__ __forceinline__ float b2f(u16 v) {
  union { u32 u; float f; } c; c.u = ((u32)v) << 16; return c.f;
}
__device__ __forceinline__ u16 f2b(float f) {
  union { float f; u32 u; } c; c.f = f;
  u32 u = c.u;
  u += 0x7fffu + ((u >> 16) & 1u);   // round-to-nearest-even
  return (u16)(u >> 16);
}

// ---------------- mega prologue: prep (774) + f2bf (8192) + hist (2048) ----------------
// Three independent kernels packed into one dispatch (launch-gap reduction).
__global__ __launch_bounds__(256)
void prologue_kernel(const float* __restrict__ Wl1, const float* __restrict__ Wl2,
                     const float* __restrict__ Wq,  const float* __restrict__ Wk,
                     const float* __restrict__ Wv,  const float* __restrict__ Wo,
                     const float* __restrict__ Wf1, const float* __restrict__ Wf2,
                     const float* __restrict__ bl1, const float* __restrict__ bl2,
                     const float* __restrict__ bq,  const float* __restrict__ bk,
                     const float* __restrict__ bv,  const float* __restrict__ bo,
                     const float* __restrict__ bf1, const float* __restrict__ bf2,
                     u16* __restrict__ Bt, float* __restrict__ biasAll,
                     const float* __restrict__ x, u16* __restrict__ xb,
                     const int* __restrict__ dstv, int* __restrict__ deg, int E) {
  int bid = blockIdx.x;
  if (bid < 774) {
    int idx = bid * 256 + threadIdx.x;
    if (idx < 196608) {
      const float* W; int local, K, N;
      if      (idx <  32768) { W = Wl1; local = idx;          K = 128; N = 256; }
      else if (idx <  65536) { W = Wl2; local = idx - 32768;  K = 256; N = 128; }
      else if (idx <  81920) { W = Wq;  local = idx - 65536;  K = 128; N = 128; }
      else if (idx <  98304) { W = Wk;  local = idx - 81920;  K = 128; N = 128; }
      else if (idx < 114688) { W = Wv;  local = idx - 98304;  K = 128; N = 128; }
      else if (idx < 131072) { W = Wo;  local = idx - 114688; K = 128; N = 128; }
      else if (idx < 163840) { W = Wf1; local = idx - 131072; K = 128; N = 256; }
      else                   { W = Wf2; local = idx - 163840; K = 256; N = 128; }
      int ks2 = (K == 256) ? 3 : 2;
      int tile = local >> 9, within = local & 511;
      int nr = within >> 5, kc = within & 31;
      int n = ((tile >> ks2) << 4) + nr;
      int k = ((tile & ((1 << ks2) - 1)) << 5) + kc;
      Bt[idx] = f2b(W[(size_t)k * N + n]);
    }
    int t = idx - 196608;
    if (t >= 0 && t < 1280) {
      float v;
      if      (t <  256) v = bl1[t];
      else if (t <  384) v = bl2[t - 256];
      else if (t <  512) v = bq[t - 384];
      else if (t <  640) v = bk[t - 512];
      else if (t <  768) v = bv[t - 640];
      else if (t <  896) v = bo[t - 768];
      else if (t < 1152) v = bf1[t - 896];
      else               v = bf2[t - 1152];
      biasAll[t] = v;
    }
  } else if (bid < 774 + 8192) {
    // fp32 row-major -> bf16 tile layout
    int i = (bid - 774) * 256 + threadIdx.x;
    int el = i * 2;
    int m = ((el >> 11) << 4) | ((el >> 5) & 15);
    int n = (((el >> 9) & 3) << 5) | (el & 31);
    float2 v = *(const float2*)(x + (size_t)m * 128 + n);
    *(u32*)(xb + el) = (u32)f2b(v.x) | ((u32)f2b(v.y) << 16);
  } else {
    int i = (bid - 774 - 8192) * 256 + threadIdx.x;
    if (i < E) atomicAdd(&deg[dstv[i]], 1);
  }
}

// ---------------- CSR scans ----------------
__global__ __launch_bounds__(256)
void scan1_kernel(const int* __restrict__ deg, int* __restrict__ bsum) {
  int t = threadIdx.x, b = blockIdx.x;
  int v = deg[b * 256 + t];
#pragma unroll
  for (int off = 1; off < 64; off <<= 1) v += __shfl_xor(v, off);
  __shared__ int wsum[4];
  if ((t & 63) == 0) wsum[t >> 6] = v;
  __syncthreads();
  if (t == 0) bsum[b] = wsum[0] + wsum[1] + wsum[2] + wsum[3];
}

__global__ void scan2_kernel(const int* __restrict__ bsum, int* __restrict__ boff,
                             int* __restrict__ rowptrN) {
  __shared__ int sh[128];
  int t = threadIdx.x;
  int v = bsum[t];
  sh[t] = v;
  __syncthreads();
  for (int off = 1; off < 128; off <<= 1) {
    int u = (t >= off) ? sh[t - off] : 0;
    __syncthreads();
    sh[t] += u;
    __syncthreads();
  }
  boff[t] = sh[t] - v;
  if (t == 127) *rowptrN = sh[127];
}

__global__ __launch_bounds__(256)
void scan3_kernel(const int* __restrict__ deg, const int* __restrict__ boff,
                  int* __restrict__ rowptr, int* __restrict__ cursor) {
  __shared__ int sh[256];
  int t = threadIdx.x, b = blockIdx.x;
  int idx = b * 256 + t;
  int v = deg[idx];
  sh[t] = v;
  __syncthreads();
  for (int off = 1; off < 256; off <<= 1) {
    int u = (t >= off) ? sh[t - off] : 0;
    __syncthreads();
    sh[t] += u;
    __syncthreads();
  }
  int ex = sh[t] - v + boff[b];
  rowptr[idx] = ex;
  cursor[idx] = ex;
}

__global__ void scatter_kernel(const int* __restrict__ src, const int* __restrict__ dst,
                               int* __restrict__ cursor, int* __restrict__ csr, int E) {
  int i = blockIdx.x * 256 + threadIdx.x;
  if (i < E) {
    int d = dst[i];
    int pos = atomicAdd(&cursor[d], 1);
    csr[pos] = src[i];
  }
}

// -------- aggregate neighbours (bf16 tile-layout gather) + (1+eps)*x --------
__global__ __launch_bounds__(256)
void agg_kernel(const u16* __restrict__ xb, const float* __restrict__ x,
                const int* __restrict__ csr, const int* __restrict__ rowptr,
                const float* __restrict__ eps, u16* __restrict__ hin, int N) {
  int node = blockIdx.x * 4 + (threadIdx.x >> 6);
  if (node >= N) return;
  int lane = threadIdx.x & 63;
  int laneoff = (lane >> 4) * 512 + (lane & 15) * 2;
  float ep1 = 1.0f + eps[0];
  int s0 = rowptr[node], s1 = rowptr[node + 1];
  float a0 = 0.f, a1 = 0.f;
  int e = s0;
  for (; e + 4 <= s1; e += 4) {
    int i0 = csr[e], i1 = csr[e + 1], i2 = csr[e + 2], i3 = csr[e + 3];
    u32 w0 = *(const u32*)(xb + (size_t)(i0 >> 4) * 2048 + (i0 & 15) * 32 + laneoff);
    u32 w1 = *(const u32*)(xb + (size_t)(i1 >> 4) * 2048 + (i1 & 15) * 32 + laneoff);
    u32 w2 = *(const u32*)(xb + (size_t)(i2 >> 4) * 2048 + (i2 & 15) * 32 + laneoff);
    u32 w3 = *(const u32*)(xb + (size_t)(i3 >> 4) * 2048 + (i3 & 15) * 32 + laneoff);
    a0 += b2f((u16)w0) + b2f((u16)w1) + b2f((u16)w2) + b2f((u16)w3);
    a1 += b2f((u16)(w0 >> 16)) + b2f((u16)(w1 >> 16))
        + b2f((u16)(w2 >> 16)) + b2f((u16)(w3 >> 16));
  }
  for (; e < s1; e++) {
    int s = csr[e];
    u32 w = *(const u32*)(xb + (size_t)(s >> 4) * 2048 + (s & 15) * 32 + laneoff);
    a0 += b2f((u16)w);
    a1 += b2f((u16)(w >> 16));
  }
  float2 xw = *(const float2*)(x + (size_t)node * 128 + lane * 2);
  a0 += ep1 * xw.x;
  a1 += ep1 * xw.y;
  *(u32*)(hin + (size_t)(node >> 4) * 2048 + (node & 15) * 32 + laneoff)
      = (u32)f2b(a0) | ((u32)f2b(a1) << 16);
}

// ---------------- tile-layout MFMA GEMM v3 (round-13, unchanged) ----------------
template<int K>
__global__ __launch_bounds__(256)
void gemm_fast(const u16* __restrict__ A, const u16* __restrict__ Bt,
               const float* __restrict__ bias, const u16* __restrict__ residb,
               u16* __restrict__ C0,
               float* __restrict__ ssum, float* __restrict__ ssq,
               int ntshift, int relu) {
  const int tid = threadIdx.x, wave = tid >> 6, lane = tid & 63;
  const int quad = lane >> 4, c = lane & 15;
  const int ntv = blockIdx.y;
  const int nc32 = 1 << ntshift;          // Nout/32
  constexpr int KT = K >> 5;
  const float* bp = bias;
  u16* C = C0;
  const int row0 = blockIdx.x * 128 + wave * 32;
  const int mt0 = row0 >> 4;
  const int col0 = ntv * 32;
  const int loff = c * 32 + quad * 8;

  const u16* Ap0 = A  + (size_t)(mt0)     * KT * 512 + loff;
  const u16* Ap1 = A  + (size_t)(mt0 + 1) * KT * 512 + loff;
  const u16* Bp0 = Bt + (size_t)(ntv * 2)     * KT * 512 + loff;
  const u16* Bp1 = Bt + (size_t)(ntv * 2 + 1) * KT * 512 + loff;

  f32x4 acc[2][2];
#pragma unroll
  for (int i = 0; i < 2; i++)
#pragma unroll
    for (int j = 0; j < 2; j++)
#pragma unroll
      for (int r = 0; r < 4; r++) acc[i][j][r] = 0.f;

#pragma unroll
  for (int i = 0; i < KT; i++) {
    short8 a0 = *(const short8*)(Ap0 + i * 512);
    short8 a1 = *(const short8*)(Ap1 + i * 512);
    short8 b0 = *(const short8*)(Bp0 + i * 512);
    short8 b1 = *(const short8*)(Bp1 + i * 512);
    acc[0][0] = __builtin_amdgcn_mfma_f32_16x16x32_bf16(a0, b0, acc[0][0], 0, 0, 0);
    acc[0][1] = __builtin_amdgcn_mfma_f32_16x16x32_bf16(a0, b1, acc[0][1], 0, 0, 0);
    acc[1][0] = __builtin_amdgcn_mfma_f32_16x16x32_bf16(a1, b0, acc[1][0], 0, 0, 0);
    acc[1][1] = __builtin_amdgcn_mfma_f32_16x16x32_bf16(a1, b1, acc[1][1], 0, 0, 0);
  }

#pragma unroll
  for (int ci = 0; ci < 2; ci++) {
    int col = col0 + ci * 16 + c;
    float bv = bp[col];
    float sp = 0.f, qp = 0.f;
#pragma unroll
    for (int mi = 0; mi < 2; mi++) {
#pragma unroll
      for (int r = 0; r < 4; r++) {
        float v = acc[mi][ci][r] + bv;
        if (relu) v = fmaxf(v, 0.f);
        if (residb)
          v += b2f(residb[((size_t)(mt0 + mi) * 4 + (col >> 5)) * 512
                          + (quad * 4 + r) * 32 + (col & 31)]);
        size_t cidx = ((size_t)(mt0 + mi) * nc32 + ntv) * 512
                    + (quad * 4 + r) * 32 + ci * 16 + c;
        C[cidx] = f2b(v);
        sp += v; qp += v * v;
      }
    }
    if (ssum) {
      sp += __shfl_xor(sp, 16); sp += __shfl_xor(sp, 32);
      qp += __shfl_xor(qp, 16); qp += __shfl_xor(qp, 32);
      if (quad == 0) {
        atomicAdd(&ssum[col], sp);
        atomicAdd(&ssq[col], qp);
      }
    }
  }
}

// ---------------- dual dispatch: t1-GEMM (y<8) + QKV-GEMM (y in 8..19) ----------------
// Independent producers merged into one launch. K=128 both. QKV writes
// head-major [b][h][j][dh]; q pre-scaled by qscl.
__global__ __launch_bounds__(256)
void gemm_t1qkv(const u16* __restrict__ hin, const u16* __restrict__ xb,
                const u16* __restrict__ BtAll, const float* __restrict__ biasAll,
                u16* __restrict__ t1, u16* __restrict__ qb, u16* __restrict__ kb,
                u16* __restrict__ vb, float qscl) {
  const int tid = threadIdx.x, wave = tid >> 6, lane = tid & 63;
  const int quad = lane >> 4, c = lane & 15;
  const int y = blockIdx.y;
  const u16* A; const u16* Btp; const float* bp; u16* C;
  int ntv, nc32, relu, headmajor; float scl;
  if (y < 8) {
    A = hin; Btp = BtAll; bp = biasAll; C = t1;
    ntv = y; nc32 = 8; relu = 1; headmajor = 0; scl = 1.0f;
  } else {
    int y2 = y - 8, ti = y2 >> 2;
    ntv = y2 & 3; A = xb;
    Btp = BtAll + 65536 + ti * 16384;
    bp = biasAll + 384 + ti * 128;
    C = (ti == 0) ? qb : ((ti == 1) ? kb : vb);
    nc32 = 4; relu = 0; headmajor = 1; scl = (ti == 0) ? qscl : 1.0f;
  }
  const int row0 = blockIdx.x * 128 + wave * 32;
  const int mt0 = row0 >> 4;
  const int col0 = ntv * 32;
  const int loff = c * 32 + quad * 8;

  const u16* Ap0 = A   + (size_t)(mt0)     * 4 * 512 + loff;
  const u16* Ap1 = A   + (size_t)(mt0 + 1) * 4 * 512 + loff;
  const u16* Bp0 = Btp + (size_t)(ntv * 2)     * 4 * 512 + loff;
  const u16* Bp1 = Btp + (size_t)(ntv * 2 + 1) * 4 * 512 + loff;

  f32x4 acc[2][2];
#pragma unroll
  for (int i = 0; i < 2; i++)
#pragma unroll
    for (int j = 0; j < 2; j++)
#pragma unroll
      for (int r = 0; r < 4; r++) acc[i][j][r] = 0.f;

#pragma unroll
  for (int i = 0; i < 4; i++) {
    short8 a0 = *(const short8*)(Ap0 + i * 512);
    short8 a1 = *(const short8*)(Ap1 + i * 512);
    short8 b0 = *(const short8*)(Bp0 + i * 512);
    short8 b1 = *(const short8*)(Bp1 + i * 512);
    acc[0][0] = __builtin_amdgcn_mfma_f32_16x16x32_bf16(a0, b0, acc[0][0], 0, 0, 0);
    acc[0][1] = __builtin_amdgcn_mfma_f32_16x16x32_bf16(a0, b1, acc[0][1], 0, 0, 0);
    acc[1][0] = __builtin_amdgcn_mfma_f32_16x16x32_bf16(a1, b0, acc[1][0], 0, 0, 0);
    acc[1][1] = __builtin_amdgcn_mfma_f32_16x16x32_bf16(a1, b1, acc[1][1], 0, 0, 0);
  }

#pragma unroll
  for (int ci = 0; ci < 2; ci++) {
    int col = col0 + ci * 16 + c;
    float bv = bp[col];
#pragma unroll
    for (int mi = 0; mi < 2; mi++) {
#pragma unroll
      for (int r = 0; r < 4; r++) {
        int m = row0 + mi * 16 + quad * 4 + r;
        float v = acc[mi][ci][r] + bv;
        if (relu) v = fmaxf(v, 0.f);
        v *= scl;
        size_t cidx;
        if (headmajor) {
          int bb = m >> 9, j = m & 511;
          cidx = (size_t)(bb * 8 + (col >> 4)) * 8192 + (size_t)j * 16 + (col & 15);
        } else {
          cidx = ((size_t)(mt0 + mi) * nc32 + ntv) * 512
               + (quad * 4 + r) * 32 + ci * 16 + c;
        }
        C[cidx] = f2b(v);
      }
    }
  }
}

// ---------------- MFMA attention v9 ----------------
// One block per (b,h) (grid 512), ALL 4 q-tiles per wave in one jp sweep:
// K-frag loads and Vt reads halved vs v8 (K read once per (b,h)).
__global__ __launch_bounds__(512)
void attn_kernel(const u16* __restrict__ Q, const u16* __restrict__ Km,
                 const u16* __restrict__ Vm, u16* __restrict__ O) {
  __shared__ __align__(16) u16 Vt[16 * 520];    // V^T [d][j'], row stride 520
  __shared__ __align__(16) u16 Psh[8][16 * 40]; // per-wave P
  const int bh = blockIdx.x;
  const int b = bh >> 3, hh = bh & 7;
  const size_t qkvbase = (size_t)bh * 8192;     // [b][h][512][16]
  const int tid = threadIdx.x;

  {
    int g = tid >> 5, i = (tid >> 1) & 15, dh = tid & 1;
    int jA = g * 32 + i;
    const u16* vp = Vm + qkvbase + (size_t)jA * 16 + dh * 8;
    short8 rowA = *(const short8*)(vp);
    short8 rowB = *(const short8*)(vp + 256);
    int j2 = g * 32 + 2 * i;
#pragma unroll
    for (int d = 0; d < 8; d++)
      *(u32*)&Vt[(dh * 8 + d) * 520 + j2] =
          (u32)(u16)rowA[d] | ((u32)(u16)rowB[d] << 16);
  }
  __syncthreads();

  const int wave = tid >> 6, lane = tid & 63;
  const int quad = lane >> 4, c = lane & 15;
  u16* Pw = &Psh[wave][0];
  u32* Pw32 = (u32*)Pw;

  short8 ones;
#pragma unroll
  for (int i = 0; i < 8; i++) ones[i] = (short)0x3F80;   // bf16 1.0
  const f32x4 zero = {0.f, 0.f, 0.f, 0.f};

  short8 qf[4];
  f32x4 accO[4], accL[4];
#pragma unroll
  for (int t = 0; t < 4; t++) {
    qf[t] = (short8)0;
    accO[t] = zero; accL[t] = zero;
    int qt = wave + t * 8;
    if (quad < 2)
      qf[t] = *(const short8*)(Q + qkvbase + (size_t)(qt * 16 + c) * 16 + quad * 8);
  }

  for (int jp = 0; jp < 16; jp++) {
    short8 kf0 = (short8)0, kf1 = (short8)0;
    if (quad < 2) {
      kf0 = *(const short8*)(Km + qkvbase + (size_t)(jp * 32 + c) * 16 + quad * 8);
      kf1 = *(const short8*)(Km + qkvbase + (size_t)(jp * 32 + 16 + c) * 16 + quad * 8);
    }
    short8 vf = *(const short8*)&Vt[c * 520 + jp * 32 + quad * 8];
#pragma unroll
    for (int t = 0; t < 4; t++) {
      f32x4 s0 = __builtin_amdgcn_mfma_f32_16x16x32_bf16(qf[t], kf0, zero, 0, 0, 0);
      f32x4 s1 = __builtin_amdgcn_mfma_f32_16x16x32_bf16(qf[t], kf1, zero, 0, 0, 0);
#pragma unroll
      for (int r = 0; r < 4; r++) {
        union { float f; u32 u; } u0, u1;
        u0.f = exp2f(s0[r]);
        u1.f = exp2f(s1[r]);
        Pw32[(quad * 4 + r) * 20 + c] = __builtin_amdgcn_perm(u1.u, u0.u, 0x07060302u);
      }
      short8 pf = *(const short8*)&Pw[c * 40 + quad * 8];
      accO[t] = __builtin_amdgcn_mfma_f32_16x16x32_bf16(pf, vf, accO[t], 0, 0, 0);
      accL[t] = __builtin_amdgcn_mfma_f32_16x16x32_bf16(pf, ones, accL[t], 0, 0, 0);
    }
  }
  // O (m = b*512 + qt*16 + quad*4 + r, n = hh*16 + c) in tile layout
#pragma unroll
  for (int t = 0; t < 4; t++) {
    int qt = wave + t * 8;
#pragma unroll
    for (int r = 0; r < 4; r++) {
      float o = accO[t][r] / accL[t][r];
      size_t oidx = ((size_t)(b * 32 + qt) * 4 + (hh >> 1)) * 512
                  + (quad * 4 + r) * 32 + (hh & 1) * 16 + c;
      O[oidx] = f2b(o);
    }
  }
}

// ---------------- fused BN elementwise (tile layout in/out) ----------------
__global__ __launch_bounds__(256)
void combine_kernel(const u16* __restrict__ y1, const u16* __restrict__ y2,
                    const float* __restrict__ stats,
                    const float* __restrict__ g1, const float* __restrict__ be1,
                    const float* __restrict__ g2, const float* __restrict__ be2,
                    u16* __restrict__ hout, float invM) {
  int i = blockIdx.x * 256 + threadIdx.x;
  int e0 = i * 2;
  int c = (((e0 >> 9) & 3) << 5) | (e0 & 31);
  float sc1a, sh1a, sc1b, sh1b, sc2a, sh2a, sc2b, sh2b;
  {
    float m = stats[c] * invM, vv = stats[128 + c] * invM - m * m;
    sc1a = g1[c] * rsqrtf(vv + 1e-5f); sh1a = be1[c] - m * sc1a;
    m = stats[c + 1] * invM; vv = stats[129 + c] * invM - m * m;
    sc1b = g1[c + 1] * rsqrtf(vv + 1e-5f); sh1b = be1[c + 1] - m * sc1b;
    m = stats[256 + c] * invM; vv = stats[384 + c] * invM - m * m;
    sc2a = g2[c] * rsqrtf(vv + 1e-5f); sh2a = be2[c] - m * sc2a;
    m = stats[257 + c] * invM; vv = stats[385 + c] * invM - m * m;
    sc2b = g2[c + 1] * rsqrtf(vv + 1e-5f); sh2b = be2[c + 1] - m * sc2b;
  }
  u32 w1 = *(const u32*)(y1 + e0);
  u32 w2 = *(const u32*)(y2 + e0);
  float r0 = b2f((u16)w1) * sc1a + sh1a + b2f((u16)w2) * sc2a + sh2a;
  float r1 = b2f((u16)(w1 >> 16)) * sc1b + sh1b + b2f((u16)(w2 >> 16)) * sc2b + sh2b;
  *(u32*)(hout + e0) = (u32)f2b(r0) | ((u32)f2b(r1) << 16);
}

// out = bn3(y3): y3 tile layout, out row-major fp32
__global__ __launch_bounds__(256)
void norm_kernel(const u16* __restrict__ y3, const float* __restrict__ stats3,
                 const float* __restrict__ g3, const float* __restrict__ be3,
                 float* __restrict__ outp, float invM) {
  int i = blockIdx.x * 256 + threadIdx.x;
  int e0 = i * 2;
  int m = ((e0 >> 11) << 4) | ((e0 >> 5) & 15);
  int c = (((e0 >> 9) & 3) << 5) | (e0 & 31);
  float mm = stats3[c] * invM, vv = stats3[128 + c] * invM - mm * mm;
  float sca = g3[c] * rsqrtf(vv + 1e-5f), sha = be3[c] - mm * sca;
  mm = stats3[c + 1] * invM; vv = stats3[129 + c] * invM - mm * mm;
  float scb = g3[c + 1] * rsqrtf(vv + 1e-5f), shb = be3[c + 1] - mm * scb;
  u32 w = *(const u32*)(y3 + e0);
  float2 r;
  r.x = b2f((u16)w) * sca + sha;
  r.y = b2f((u16)(w >> 16)) * scb + shb;
  *(float2*)(outp + (size_t)m * 128 + c) = r;
}

// ---------------- launch ----------------
extern "C" void kernel_launch(void* const* d_in, const int* in_sizes, int n_in,
                              void* d_out, int out_size, void* d_ws, size_t ws_size,
                              hipStream_t stream) {
  const float* x   = (const float*)d_in[0];
  const int*   ei  = (const int*)d_in[1];
  const float* eps = (const float*)d_in[2];
  const float* Wl1 = (const float*)d_in[3];  const float* bl1 = (const float*)d_in[4];
  const float* Wl2 = (const float*)d_in[5];  const float* bl2 = (const float*)d_in[6];
  const float* g1  = (const float*)d_in[7];  const float* be1 = (const float*)d_in[8];
  const float* Wq  = (const float*)d_in[9];  const float* bq  = (const float*)d_in[10];
  const float* Wk  = (const float*)d_in[11]; const float* bk  = (const float*)d_in[12];
  const float* Wv  = (const float*)d_in[13]; const float* bv  = (const float*)d_in[14];
  const float* Wo  = (const float*)d_in[15]; const float* bo  = (const float*)d_in[16];
  const float* g2  = (const float*)d_in[17]; const float* be2 = (const float*)d_in[18];
  const float* Wf1 = (const float*)d_in[19]; const float* bf1 = (const float*)d_in[20];
  const float* Wf2 = (const float*)d_in[21]; const float* bf2 = (const float*)d_in[22];
  const float* g3  = (const float*)d_in[23]; const float* be3 = (const float*)d_in[24];
  float* out = (float*)d_out;

  const int N = in_sizes[0] / 128;   // 32768
  const int E = in_sizes[1] / 2;     // 524288
  const size_t MB = 1048576;
  const float invM = 1.0f / (float)N;

  char* ws = (char*)d_ws;
  u16* hin = (u16*)(ws + 0);          // [N,128] tile; agg out, later o_attn
  u16* t1  = (u16*)(ws + 8 * MB);     // [N,256] tile; later t2. CSR overlays pre-GEMM:
  int* deg    = (int*)(ws + 8 * MB);
  int* rowptr = (int*)(ws + 8 * MB + 256 * 1024);
  int* cursor = (int*)(ws + 8 * MB + 512 * 1024);
  int* csr    = (int*)(ws + 8 * MB + 768 * 1024);  // E ints = 2MB
  u16* qb  = (u16*)(ws + 24 * MB);    // q (head-major); later h_comb (tile)
  u16* kb  = (u16*)(ws + 32 * MB);    // k (head-major); later y3 (tile)
  u16* vb  = (u16*)(ws + 40 * MB);    // v (head-major)
  u16* xb  = (u16*)(ws + 48 * MB);    // bf16 x (tile); later y2 in-place
  u16* y2  = xb;
  float* stats = (float*)(ws + 56 * MB);         // s1,q1,s2,q2,s3,q3 (6*128)
  int* bsum = (int*)(ws + 56 * MB + 8192);
  int* boff = (int*)(ws + 56 * MB + 8192 + 512);
  u16* y1 = (u16*)d_out;              // d_out[0..8MB) as bf16 tile scratch
  u16*   BtAll   = (u16*)((char*)d_out + 8 * MB);                // 384 KB W^T tiles
  float* biasAll = (float*)((char*)d_out + 8 * MB + 400 * 1024); // 5 KB

  hipMemsetAsync(deg, 0, (size_t)N * sizeof(int), stream);
  hipMemsetAsync(stats, 0, 6 * 128 * sizeof(float), stream);

  const int* srcv = ei;
  const int* dstv = ei + E;
  const float QSCL = 0.25f * 1.44269504088896f;   // score scale * log2(e)

  // prologue: prep (774) + f2bf (8192) + hist (2048) in one dispatch
  prologue_kernel<<<774 + 8192 + 2048, 256, 0, stream>>>(
      Wl1, Wl2, Wq, Wk, Wv, Wo, Wf1, Wf2,
      bl1, bl2, bq, bk, bv, bo, bf1, bf2,
      BtAll, biasAll, x, xb, dstv, deg, E);
  scan1_kernel<<<N / 256, 256, 0, stream>>>(deg, bsum);
  scan2_kernel<<<1, 128, 0, stream>>>(bsum, boff, rowptr + N);
  scan3_kernel<<<N / 256, 256, 0, stream>>>(deg, boff, rowptr, cursor);
  scatter_kernel<<<(E + 255) / 256, 256, 0, stream>>>(srcv, dstv, cursor, csr, E);
  agg_kernel<<<N / 4, 256, 0, stream>>>(xb, x, csr, rowptr, eps, hin, N);

  dim3 blk(256);
  // t1 = relu(hin @ Wl1 + bl1)  AND  q,k,v (head-major) in one dispatch
  gemm_t1qkv<<<dim3(N / 128, 20), blk, 0, stream>>>(hin, xb, BtAll, biasAll,
                                                    t1, qb, kb, vb, QSCL);
  // y1 = xb + t1 @ Wl2 + bl2  (+stats1)  Nout=128
  gemm_fast<256><<<dim3(N / 128, 4), blk, 0, stream>>>(t1, BtAll + 32768, biasAll + 256,
      xb, y1, stats + 0, stats + 128, 2, 0);
  // attention -> o_attn (tile layout, reuse hin); one block per (b,h)
  attn_kernel<<<(N / 512) * 8, dim3(512), 0, stream>>>(qb, kb, vb, hin);
  // y2 = xb + o_attn @ Wo + bo  (+stats2)  (in-place over xb, same-thread RMW)
  gemm_fast<128><<<dim3(N / 128, 4), blk, 0, stream>>>(hin, BtAll + 114688, biasAll + 768,
      xb, y2, stats + 256, stats + 384, 2, 0);
  // h = bn1(y1) + bn2(y2)  -> qb   (BN params inline)
  combine_kernel<<<(N * 128 / 2) / 256, blk, 0, stream>>>(y1, y2, stats,
      g1, be1, g2, be2, qb, invM);
  // t2 = relu(h @ Wf1 + bf1)            Nout=256
  gemm_fast<128><<<dim3(N / 128, 8), blk, 0, stream>>>(qb, BtAll + 131072, biasAll + 896,
      nullptr, t1, nullptr, nullptr, 3, 1);
  // y3 = qb + t2 @ Wf2 + bf2  (+stats3)  -> kb
  gemm_fast<256><<<dim3(N / 128, 4), blk, 0, stream>>>(t1, BtAll + 163840, biasAll + 1152,
      qb, kb, stats + 512, stats + 640, 2, 0);
  // out = bn3(y3)   (BN params inline)
  norm_kernel<<<(N * 128 / 2) / 256, blk, 0, stream>>>(kb, stats + 512, g3, be3, out, invM);
}